// Round 3
// baseline (231.986 us; speedup 1.0000x reference)
//
#include <hip/hip_runtime.h>

// Problem constants (fixed by setup_inputs): B=8, P=25000, C=81, E=256, N=B*P=200000
#define N_TOT   200000
#define C_CLS   81
#define P_PER   25000
#define CM1     80            // C-1

// Output layout (float32 elements, concatenated in return order):
//   boxes   [N,80,4]  -> offset 0,           size 64,000,000
//   scores  [N,80]    -> offset 64,000,000,  size 16,000,000
//   id_embs [N,256]   -> offset 80,000,000,  size 51,200,000
//   labels  [N,80]    -> offset 131,200,000, size 16,000,000
//   roi     [N,80]    -> offset 147,200,000, size 16,000,000

typedef float f4 __attribute__((ext_vector_type(4)));

// Fused grid partition (256-thread blocks):
//   [0, 62500)            decode: 16,000,000 threads, one box each
//   [62500, 112500)       softmax: 4 rows/block (one wave64 per row), 200,000 rows
//   [112500, 137500)      id copy: 2 float4/thread, 12,800,000 float4 total
#define DEC_BLOCKS 62500u
#define SM_BLOCKS  50000u
#define CP_BLOCKS  25000u
#define CP_HALF    6400000u   // float4s per half

__global__ __launch_bounds__(256) void fused_kernel(
    const float* __restrict__ logits,      // [N, 81]
    const f4*    __restrict__ box_reg4,    // [N, 81] float4 rows
    const f4*    __restrict__ id_emb4,     // [N*64] float4
    const f4*    __restrict__ proposals4,  // [N]
    const int*   __restrict__ img_h_p,
    const int*   __restrict__ img_w_p,
    float* __restrict__ out)
{
    f4*    out_boxes  = (f4*)out;                   // [16M] float4
    float* out_scores = out + 64000000u;
    f4*    out_ids    = (f4*)(out + 80000000u);
    float* out_labels = out + 131200000u;
    float* out_roi    = out + 147200000u;

    unsigned int b = blockIdx.x;

    if (b < DEC_BLOCKS) {
        // ---------------- decode boxes + labels + roi ----------------
        unsigned int tid  = b * 256u + threadIdx.x;     // [0, 16,000,000) exact
        unsigned int n    = tid / CM1;
        unsigned int cidx = tid - n * CM1;              // 0..79
        unsigned int c    = cidx + 1u;                  // class 1..80

        const float Wf = (float)img_w_p[0];
        const float Hf = (float)img_h_p[0];

        // proposal row: broadcast across the 80 threads of one n -> keep cached
        const f4 pr = proposals4[n];
        float w  = pr.z - pr.x;
        float h  = pr.w - pr.y;
        float cx = pr.x + 0.5f * w;
        float cy = pr.y + 0.5f * h;

        // deltas row n: 81 aligned float4s; streamed once -> nontemporal load
        const f4 d = __builtin_nontemporal_load(&box_reg4[(size_t)n * C_CLS + c]);

        const float CLIP = 4.135166556742356f;  // log(1000/16)
        float dx = d.x * 0.1f;
        float dy = d.y * 0.1f;
        float dw = fminf(d.z * 0.2f, CLIP);
        float dh = fminf(d.w * 0.2f, CLIP);

        float pcx = dx * w + cx;
        float pcy = dy * h + cy;
        float pw  = expf(dw) * w;
        float ph  = expf(dh) * h;

        float x1 = fminf(fmaxf(pcx - 0.5f * pw, 0.0f), Wf);
        float y1 = fminf(fmaxf(pcy - 0.5f * ph, 0.0f), Hf);
        float x2 = fminf(fmaxf(pcx + 0.5f * pw, 0.0f), Wf);
        float y2 = fminf(fmaxf(pcy + 0.5f * ph, 0.0f), Hf);

        f4 bx; bx.x = x1; bx.y = y1; bx.z = x2; bx.w = y2;
        out_boxes[tid]  = bx;                       // plain cached stores
        out_labels[tid] = (float)c;
        out_roi[tid]    = (float)(n % P_PER);
    } else if (b < DEC_BLOCKS + SM_BLOCKS) {
        // ---------------- softmax over 81 classes, drop class 0 ----------------
        unsigned int wave = (b - DEC_BLOCKS) * 4u + (threadIdx.x >> 6);  // row id, exact
        unsigned int lane = threadIdx.x & 63u;

        const float* row = logits + (size_t)wave * C_CLS;
        float v0 = __builtin_nontemporal_load(&row[lane]);
        float v1 = (lane < 17u) ? __builtin_nontemporal_load(&row[64u + lane]) : -INFINITY;

        float m = fmaxf(v0, v1);
        #pragma unroll
        for (int off = 32; off; off >>= 1) m = fmaxf(m, __shfl_xor(m, off, 64));

        float e0 = expf(v0 - m);
        float e1 = (lane < 17u) ? expf(v1 - m) : 0.0f;

        float s = e0 + e1;
        #pragma unroll
        for (int off = 32; off; off >>= 1) s += __shfl_xor(s, off, 64);

        float inv = 1.0f / s;
        float* o = out_scores + (size_t)wave * CM1;
        if (lane >= 1u) o[lane - 1u] = e0 * inv;
        if (lane < 17u) o[63u + lane] = e1 * inv;
    } else {
        // ---------------- id_embedding copy: 2 float4 per thread ----------------
        unsigned int i = (b - DEC_BLOCKS - SM_BLOCKS) * 256u + threadIdx.x; // [0, 6.4M)
        f4 a0 = __builtin_nontemporal_load(&id_emb4[i]);
        f4 a1 = __builtin_nontemporal_load(&id_emb4[i + CP_HALF]);
        out_ids[i]           = a0;
        out_ids[i + CP_HALF] = a1;
    }
}

extern "C" void kernel_launch(void* const* d_in, const int* in_sizes, int n_in,
                              void* d_out, int out_size, void* d_ws, size_t ws_size,
                              hipStream_t stream) {
    const float* class_logits = (const float*)d_in[0];  // [N,81]
    const float* box_reg      = (const float*)d_in[1];  // [N,324]
    const float* id_emb       = (const float*)d_in[2];  // [N,256]
    const float* proposals    = (const float*)d_in[3];  // [N,4]
    const int*   img_h        = (const int*)d_in[4];
    const int*   img_w        = (const int*)d_in[5];

    dim3 grid(DEC_BLOCKS + SM_BLOCKS + CP_BLOCKS), block(256);
    fused_kernel<<<grid, block, 0, stream>>>(
        class_logits, (const f4*)box_reg, (const f4*)id_emb, (const f4*)proposals,
        img_h, img_w, (float*)d_out);
}

// Round 4
// 219.058 us; speedup vs baseline: 1.0590x; 1.0590x over previous
//
#include <hip/hip_runtime.h>

// Problem constants (fixed by setup_inputs): B=8, P=25000, C=81, E=256, N=B*P=200000
#define N_TOT   200000
#define C_CLS   81
#define P_PER   25000
#define CM1     80            // C-1

// Output layout (float32 elements, concatenated in return order):
//   boxes   [N,80,4]  -> offset 0,           size 64,000,000
//   scores  [N,80]    -> offset 64,000,000,  size 16,000,000
//   id_embs [N,256]   -> offset 80,000,000,  size 51,200,000
//   labels  [N,80]    -> offset 131,200,000, size 16,000,000
//   roi     [N,80]    -> offset 147,200,000, size 16,000,000

typedef float f4 __attribute__((ext_vector_type(4)));

// Fused grid partition (256-thread blocks):
//   [0, 62500)                 decode: 16,000,000 threads, one box each (boxes only)
//   [62500, 112500)            softmax: 4 rows/block (one wave64 per row), 200,000 rows
//   [112500, 137500)           id copy: 2 float4/thread, 12,800,000 float4 total
//   [137500, 153125)           labels+roi fill: 4,000,000 threads, 1 float4 each stream
#define DEC_BLOCKS 62500u
#define SM_BLOCKS  50000u
#define CP_BLOCKS  25000u
#define LR_BLOCKS  15625u
#define CP_HALF    6400000u   // float4s per half of id_emb

__global__ __launch_bounds__(256) void fused_kernel(
    const float* __restrict__ logits,      // [N, 81]
    const f4*    __restrict__ box_reg4,    // [N, 81] float4 rows
    const f4*    __restrict__ id_emb4,     // [N*64] float4
    const f4*    __restrict__ proposals4,  // [N]
    const int*   __restrict__ img_h_p,
    const int*   __restrict__ img_w_p,
    float* __restrict__ out)
{
    f4*    out_boxes   = (f4*)out;                  // [16M] float4
    float* out_scores  = out + 64000000u;
    f4*    out_ids     = (f4*)(out + 80000000u);
    f4*    out_labels4 = (f4*)(out + 131200000u);   // [4M] float4
    f4*    out_roi4    = (f4*)(out + 147200000u);   // [4M] float4

    unsigned int b = blockIdx.x;

    if (b < DEC_BLOCKS) {
        // ---------------- decode boxes (boxes stream only) ----------------
        unsigned int tid  = b * 256u + threadIdx.x;     // [0, 16,000,000) exact
        unsigned int n    = tid / CM1;
        unsigned int cidx = tid - n * CM1;              // 0..79
        unsigned int c    = cidx + 1u;                  // class 1..80

        const float Wf = (float)img_w_p[0];
        const float Hf = (float)img_h_p[0];

        // proposal row: broadcast across the 80 threads of one n -> keep cached
        const f4 pr = proposals4[n];
        float w  = pr.z - pr.x;
        float h  = pr.w - pr.y;
        float cx = pr.x + 0.5f * w;
        float cy = pr.y + 0.5f * h;

        // deltas row n: 81 aligned float4s; streamed once -> nontemporal load
        const f4 d = __builtin_nontemporal_load(&box_reg4[(size_t)n * C_CLS + c]);

        const float CLIP = 4.135166556742356f;  // log(1000/16)
        float dx = d.x * 0.1f;
        float dy = d.y * 0.1f;
        float dw = fminf(d.z * 0.2f, CLIP);
        float dh = fminf(d.w * 0.2f, CLIP);

        float pcx = dx * w + cx;
        float pcy = dy * h + cy;
        float pw  = expf(dw) * w;
        float ph  = expf(dh) * h;

        float x1 = fminf(fmaxf(pcx - 0.5f * pw, 0.0f), Wf);
        float y1 = fminf(fmaxf(pcy - 0.5f * ph, 0.0f), Hf);
        float x2 = fminf(fmaxf(pcx + 0.5f * pw, 0.0f), Wf);
        float y2 = fminf(fmaxf(pcy + 0.5f * ph, 0.0f), Hf);

        f4 bx; bx.x = x1; bx.y = y1; bx.z = x2; bx.w = y2;
        __builtin_nontemporal_store(bx, &out_boxes[tid]);
    } else if (b < DEC_BLOCKS + SM_BLOCKS) {
        // ---------------- softmax over 81 classes, drop class 0 ----------------
        unsigned int wave = (b - DEC_BLOCKS) * 4u + (threadIdx.x >> 6);  // row id, exact
        unsigned int lane = threadIdx.x & 63u;

        const float* row = logits + (size_t)wave * C_CLS;
        float v0 = __builtin_nontemporal_load(&row[lane]);
        float v1 = (lane < 17u) ? __builtin_nontemporal_load(&row[64u + lane]) : -INFINITY;

        float m = fmaxf(v0, v1);
        #pragma unroll
        for (int off = 32; off; off >>= 1) m = fmaxf(m, __shfl_xor(m, off, 64));

        float e0 = expf(v0 - m);
        float e1 = (lane < 17u) ? expf(v1 - m) : 0.0f;

        float s = e0 + e1;
        #pragma unroll
        for (int off = 32; off; off >>= 1) s += __shfl_xor(s, off, 64);

        float inv = 1.0f / s;
        float* o = out_scores + (size_t)wave * CM1;
        if (lane >= 1u) __builtin_nontemporal_store(e0 * inv, &o[lane - 1u]);
        if (lane < 17u) __builtin_nontemporal_store(e1 * inv, &o[63u + lane]);
    } else if (b < DEC_BLOCKS + SM_BLOCKS + CP_BLOCKS) {
        // ---------------- id_embedding copy: 2 float4 per thread ----------------
        unsigned int i = (b - DEC_BLOCKS - SM_BLOCKS) * 256u + threadIdx.x; // [0, 6.4M)
        f4 a0 = __builtin_nontemporal_load(&id_emb4[i]);
        f4 a1 = __builtin_nontemporal_load(&id_emb4[i + CP_HALF]);
        __builtin_nontemporal_store(a0, &out_ids[i]);
        __builtin_nontemporal_store(a1, &out_ids[i + CP_HALF]);
    } else {
        // ---------------- labels + roi pure fill, float4 stores ----------------
        // j in [0, 4,000,000): one float4 (4 cells) of labels and of roi.
        // 80 % 4 == 0 -> a float4 never crosses a row-of-80 boundary.
        unsigned int j = (b - DEC_BLOCKS - SM_BLOCKS - CP_BLOCKS) * 256u + threadIdx.x;
        unsigned int n  = j / 20u;                 // proposal row (20 float4s per row)
        unsigned int cb = (j - n * 20u) * 4u;      // cidx base: 0,4,...,76
        f4 lv; lv.x = (float)(cb + 1u); lv.y = (float)(cb + 2u);
               lv.z = (float)(cb + 3u); lv.w = (float)(cb + 4u);
        float r = (float)(n % P_PER);
        f4 rv; rv.x = r; rv.y = r; rv.z = r; rv.w = r;
        __builtin_nontemporal_store(lv, &out_labels4[j]);
        __builtin_nontemporal_store(rv, &out_roi4[j]);
    }
}

extern "C" void kernel_launch(void* const* d_in, const int* in_sizes, int n_in,
                              void* d_out, int out_size, void* d_ws, size_t ws_size,
                              hipStream_t stream) {
    const float* class_logits = (const float*)d_in[0];  // [N,81]
    const float* box_reg      = (const float*)d_in[1];  // [N,324]
    const float* id_emb       = (const float*)d_in[2];  // [N,256]
    const float* proposals    = (const float*)d_in[3];  // [N,4]
    const int*   img_h        = (const int*)d_in[4];
    const int*   img_w        = (const int*)d_in[5];

    dim3 grid(DEC_BLOCKS + SM_BLOCKS + CP_BLOCKS + LR_BLOCKS), block(256);
    fused_kernel<<<grid, block, 0, stream>>>(
        class_logits, (const f4*)box_reg, (const f4*)id_emb, (const f4*)proposals,
        img_h, img_w, (float*)d_out);
}